// Round 7
// baseline (119.627 us; speedup 1.0000x reference)
//
#include <hip/hip_runtime.h>
#include <hip/hip_bf16.h>
#include <math.h>

// ---------------------------------------------------------------------------
// SAContrastiveAdversarialLoss on MI355X (gfx950)
// B=8192, D=128, S=64. Output: scalar fp32.
//
// loss = sum_i -log(1e-12 + num_i/denom_i) / (B*(2B-1))
//        + sum_i -log(1e-12 + 1 - picked_i)
//
// v8 structure:
//  - Harness floor: ~42us 256MiB workspace re-poison fill inside the timed
//    region. Our kernels sit on top.
//  - main: 32x32x16 MFMA (ceiling 2382+ TF vs 2075 for 16x16x32; HALF the
//    MFMA instruction count -> frees issue slots for the exp2 stream).
//    Block = 256 rows x 256 cols, 8 waves (32 rows each); whole 64KB chunk
//    prestaged via global_load_lds; ONE __syncthreads; barrier-free rotated
//    free-run phases (v7 winner). T2t float4-coalesced partial stores.
//  - prep: 32 rows/block (= one fragment tile); normalize into padded LDS,
//    emit 32-row fragment tiles as contiguous coalesced 16B stores.
//    A/B operand tiling: elem(row, k) at frag[kf=k>>4][lane=(row&31)+32*((k>>3)&1)][j=k&7].
//  - final_adv: 2048 blocks, one row/wave, partial plain store; 1-block
//    reduce sums partials (r5 lesson: block-level same-addr atomics ~15us).
// ---------------------------------------------------------------------------

#define NROWS 8192
#define DFEAT 128

typedef __bf16 bf16_t;
typedef __bf16 bf16x8 __attribute__((ext_vector_type(8)));
typedef __bf16 bf16x2 __attribute__((ext_vector_type(2)));
typedef float  f32x4  __attribute__((ext_vector_type(4)));
typedef float  f32x16 __attribute__((ext_vector_type(16)));

__device__ __forceinline__ float fexp2(float x) {
#if __has_builtin(__builtin_amdgcn_exp2f)
  return __builtin_amdgcn_exp2f(x);
#else
  return exp2f(x);
#endif
}

// async global->LDS, 16B per lane. gsrc is per-lane (includes +lane*16);
// lds dst is wave-uniform base (HW adds lane*16).
__device__ __forceinline__ void stage16(const void* gsrc, void* ldst) {
  __builtin_amdgcn_global_load_lds(
      (const __attribute__((address_space(1))) unsigned int*)gsrc,
      (__attribute__((address_space(3))) unsigned int*)ldst, 16, 0, 0);
}

// ---------------------------------------------------------------------------
// prep: block = 32 rows = one 32-row fragment tile (for A, K2, K1 each).
// Phase 1: wave w normalizes rows 2w, 2w+1 into padded LDS (stride 136).
// Phase 2: 1536 coalesced bf16x8 stores emit the three fragment tiles:
//   tile elem u*8+j  (u = kf*64 + lane) = L[lane&31][kf*16 + (lane>>5)*8 + j]
// i.e. A/B operand layout: lane = (row&31) + 32*k_half, 8 contiguous k.
__global__ __launch_bounds__(1024)
void sa_prep_kernel(const float* __restrict__ z1,
                    const float* __restrict__ z2,
                    bf16_t* __restrict__ Abuf,
                    bf16_t* __restrict__ Kc,
                    float* __restrict__ numv,
                    float* __restrict__ d11v) {
  __shared__ __align__(16) bf16_t L[3][32][136];

  int wave = threadIdx.x >> 6;   // 0..15
  int lane = threadIdx.x & 63;
  int blk  = blockIdx.x;         // 0..255

  const float SCL = 14.426950408889634f;  // 10 * log2(e), folds /tau + exp2

#pragma unroll
  for (int r = 0; r < 2; ++r) {
    int rl  = wave * 2 + r;      // 0..31 row within tile
    int row = blk * 32 + rl;

    float2 a = ((const float2*)(z1 + (size_t)row * DFEAT))[lane];
    float2 b = ((const float2*)(z2 + (size_t)row * DFEAT))[lane];

    float s1  = a.x * a.x + a.y * a.y;
    float s2  = b.x * b.x + b.y * b.y;
    float s12 = a.x * b.x + a.y * b.y;
#pragma unroll
    for (int m = 32; m; m >>= 1) {
      s1  += __shfl_xor(s1, m, 64);
      s2  += __shfl_xor(s2, m, 64);
      s12 += __shfl_xor(s12, m, 64);
    }
    float r1 = 1.0f / fmaxf(sqrtf(s1), 1e-8f);  // COS_EPS
    float r2 = 1.0f / fmaxf(sqrtf(s2), 1e-8f);

    bf16x2 av;  av[0] = (bf16_t)(a.x * r1 * SCL); av[1] = (bf16_t)(a.y * r1 * SCL);
    bf16x2 k2v; k2v[0] = (bf16_t)(b.x * r2);      k2v[1] = (bf16_t)(b.y * r2);
    bf16x2 k1v; k1v[0] = (bf16_t)(a.x * r1);      k1v[1] = (bf16_t)(a.y * r1);

    *(bf16x2*)&L[0][rl][2 * lane] = av;
    *(bf16x2*)&L[1][rl][2 * lane] = k2v;
    *(bf16x2*)&L[2][rl][2 * lane] = k1v;

    if (lane == 0) {
      numv[row] = expf(10.0f * s12 * r1 * r2);
      d11v[row] = expf(10.0f * s1 * r1 * r1);
    }
  }
  __syncthreads();

  // Phase 2: 3 tiles x 512 bf16x8 stores, fully coalesced.
#pragma unroll
  for (int st = 0; st < 2; ++st) {
    int t = threadIdx.x + st * 1024;
    if (t < 1536) {
      int sel = t >> 9;          // 0=A, 1=K2, 2=K1
      int u   = t & 511;
      int lu  = u & 63;
      int kf  = u >> 6;
      bf16x8 v = *(const bf16x8*)&L[sel][lu & 31][kf * 16 + (lu >> 5) * 8];
      bf16_t* dst = (sel == 0) ? (Abuf + (size_t)blk * 4096)
                  : (sel == 1) ? (Kc + (size_t)blk * 4096)
                               : (Kc + (size_t)(256 + blk) * 4096);
      *(bf16x8*)(dst + u * 8) = v;
    }
  }
}

// ---------------------------------------------------------------------------
// main: fused "row-sum of exp(sim)" over the virtual 8192x16384 matrix.
// Block = 256 rows x 256 cols; 8 waves; wave w owns rows [bx*256+w*32, +32).
// Prologue: whole 64KB chunk of Kc staged to LDS (8 x global_load_lds per
// wave), ONE __syncthreads, then barrier-free rotated free-run phases.
// Per phase (32 cols): 8 x mfma_f32_32x32x16_bf16 (serial K chain) +
// 16 exp2 + 16 add. C/D layout: col=lane&31, row=(reg&3)+8*(reg>>2)+4*(lane>>5).
// Partial row-sums -> T2t[by][row], float4-coalesced (2 writer lanes/wave).
__global__ __launch_bounds__(512, 4)
void sa_main_kernel(const bf16_t* __restrict__ Abuf,
                    const bf16_t* __restrict__ Kc,
                    float* __restrict__ T2t) {
  __shared__ __align__(16) bf16_t bsm[32768];  // 64KB: 8 col-tiles x 8KB

  int wave = threadIdx.x >> 6;   // 0..7
  int lane = threadIdx.x & 63;

  // bijective XCD swizzle: 2048 blocks, 8 XCDs, 256 each. Each XCD sweeps
  // 8 col-chunks (512KB of Kc) + all of A (2MB) -> L2-resident.
  int id     = blockIdx.x;
  int xcd    = id & 7;
  int within = id >> 3;                 // 0..255
  int by     = xcd * 8 + (within >> 5); // 0..63 col-chunk: 256 cols
  int bx     = within & 31;             // 0..31 row-block: 256 rows
  int rowBase = bx * 256 + wave * 32;

  // A fragments: tile = bx*8 + wave (32 rows), 8 k-fragments of 1KB.
  const bf16x8* ap = (const bf16x8*)Abuf + (size_t)(bx * 8 + wave) * 512 + lane;
  bf16x8 afrag[8];
#pragma unroll
  for (int kf = 0; kf < 8; ++kf) afrag[kf] = ap[kf * 64];

  // Stage the whole 64KB chunk: wave w covers bytes [w*8KB, (w+1)*8KB).
  const char* src = (const char*)Kc + (size_t)by * 65536 +
                    (size_t)wave * 8192 + (size_t)lane * 16;
  char* dst = (char*)&bsm[0] + wave * 8192;  // wave-uniform LDS dst
#pragma unroll
  for (int i = 0; i < 8; ++i) stage16(src + i * 1024, dst + i * 1024);

  __syncthreads();  // only barrier; LDS read-only afterwards

  float sums[16];
#pragma unroll
  for (int r = 0; r < 16; ++r) sums[r] = 0.0f;

  // 8 phases x 32 cols, rotated start per wave; no sync, waves free-run.
#pragma unroll 1
  for (int i = 0; i < 8; ++i) {
    int p = (wave + i) & 7;
    const bf16x8* bs = (const bf16x8*)&bsm[0] + p * 512 + lane;
    bf16x8 bfr[8];
#pragma unroll
    for (int kf = 0; kf < 8; ++kf) bfr[kf] = bs[kf * 64];

    f32x16 c = (f32x16)(0.0f);
    __builtin_amdgcn_s_setprio(1);
#pragma unroll
    for (int kf = 0; kf < 8; ++kf)
      c = __builtin_amdgcn_mfma_f32_32x32x16_bf16(afrag[kf], bfr[kf], c,
                                                  0, 0, 0);
    __builtin_amdgcn_s_setprio(0);
#pragma unroll
    for (int r = 0; r < 16; ++r) sums[r] += fexp2(c[r]);
  }

  // Row sums: reduce across the 32 lanes of each half (cols 0..31), then
  // lane 0 (h=0) and lane 32 (h=1) hold 16 rows each:
  //   row = (reg&3) + 8*(reg>>2) + 4*h  -> four contiguous float4 groups.
#pragma unroll
  for (int r = 0; r < 16; ++r) {
    float v = sums[r];
    v += __shfl_xor(v, 1, 64);
    v += __shfl_xor(v, 2, 64);
    v += __shfl_xor(v, 4, 64);
    v += __shfl_xor(v, 8, 64);
    v += __shfl_xor(v, 16, 64);
    sums[r] = v;
  }
  if ((lane & 31) == 0) {
    int h = lane >> 5;
    float* base = T2t + (size_t)by * 8192 + rowBase;
#pragma unroll
    for (int g = 0; g < 4; ++g) {
      f32x4 st = {sums[4 * g], sums[4 * g + 1], sums[4 * g + 2],
                  sums[4 * g + 3]};
      *(f32x4*)(base + 8 * g + 4 * h) = st;
    }
  }
}

// ---------------------------------------------------------------------------
// final+adv fused: 2048 blocks x 256 threads, one row per wave, fully
// parallel. Lane l contributes T2t[l][row] (L2-resident 2MB); summed in the
// same 64-lane butterfly as the adversarial argmax. Partial -> plain store.
__global__ __launch_bounds__(256)
void sa_final_adv_kernel(const float* __restrict__ T2t,
                         const float* __restrict__ numv,
                         const float* __restrict__ d11v,
                         const float* __restrict__ c,
                         const float* __restrict__ lab,
                         float* __restrict__ partial) {
  int wave = threadIdx.x >> 6;
  int lane = threadIdx.x & 63;
  int row  = blockIdx.x * 4 + wave;

  float cv = c[row * 64 + lane];
  float lv = lab[row * 64 + lane];
  float tv = T2t[(size_t)lane * 8192 + row];  // 64 chunk-partials per row

  float ss = cv * cv;
  float bestv = lv;
  int   besti = lane;
#pragma unroll
  for (int m = 32; m; m >>= 1) {
    ss += __shfl_xor(ss, m, 64);
    tv += __shfl_xor(tv, m, 64);
    float ov = __shfl_xor(bestv, m, 64);
    int   oi = __shfl_xor(besti, m, 64);
    if (ov > bestv || (ov == bestv && oi < besti)) { bestv = ov; besti = oi; }
  }
  float picked = __shfl(cv, besti, 64) / fmaxf(sqrtf(ss), 1e-12f);

  float term = 0.0f;
  if (lane == 0) {
    float denom = tv - d11v[row];  // tv = full row sum of both exp blocks
    term = -logf(1e-12f + numv[row] / denom) * (1.0f / 134209536.0f)
           - logf(1e-12f + 1.0f - picked);  // LAM = 1
  }

  __shared__ float wacc[4];
  if (lane == 0) wacc[wave] = term;
  __syncthreads();
  if (threadIdx.x == 0)
    partial[blockIdx.x] = wacc[0] + wacc[1] + wacc[2] + wacc[3];
}

// ---------------------------------------------------------------------------
// reduce: single block sums the 2048 block partials -> out (plain store).
__global__ __launch_bounds__(256)
void sa_reduce_kernel(const float* __restrict__ partial,
                      float* __restrict__ out) {
  float v = 0.0f;
#pragma unroll
  for (int i = 0; i < 8; ++i) v += partial[threadIdx.x + 256 * i];
#pragma unroll
  for (int m = 32; m; m >>= 1) v += __shfl_xor(v, m, 64);
  __shared__ float wacc[4];
  if ((threadIdx.x & 63) == 0) wacc[threadIdx.x >> 6] = v;
  __syncthreads();
  if (threadIdx.x == 0) out[0] = wacc[0] + wacc[1] + wacc[2] + wacc[3];
}

// ---------------------------------------------------------------------------
extern "C" void kernel_launch(void* const* d_in, const int* in_sizes, int n_in,
                              void* d_out, int out_size, void* d_ws,
                              size_t ws_size, hipStream_t stream) {
  const float* z1  = (const float*)d_in[0];  // [8192,128]
  const float* z2  = (const float*)d_in[1];  // [8192,128]
  const float* co  = (const float*)d_in[2];  // [8192,64]
  const float* lab = (const float*)d_in[3];  // [8192,64]
  float* out = (float*)d_out;

  char* ws = (char*)d_ws;
  bf16_t* Abuf  = (bf16_t*)ws;                           // 8192*128*2 = 2 MB
  bf16_t* Kc    = (bf16_t*)(ws + 2u * 1024 * 1024);      // 16384*128*2 = 4 MB
  float*  T2t   = (float*)(ws + 6u * 1024 * 1024);       // 64*8192*4 = 2 MB
  float*  numv  = (float*)(ws + 8u * 1024 * 1024);       // 32 KB
  float*  d11v  = numv + NROWS;                          // 32 KB
  float*  part  = d11v + NROWS;                          // 8 KB

  sa_prep_kernel<<<NROWS / 32, 1024, 0, stream>>>(z1, z2, Abuf, Kc, numv,
                                                  d11v);
  sa_main_kernel<<<2048, 512, 0, stream>>>(Abuf, Kc, T2t);
  sa_final_adv_kernel<<<NROWS / 4, 256, 0, stream>>>(T2t, numv, d11v, co, lab,
                                                     part);
  sa_reduce_kernel<<<1, 256, 0, stream>>>(part, out);
}

// Round 8
// 111.237 us; speedup vs baseline: 1.0754x; 1.0754x over previous
//
#include <hip/hip_runtime.h>
#include <hip/hip_bf16.h>
#include <math.h>

// ---------------------------------------------------------------------------
// SAContrastiveAdversarialLoss on MI355X (gfx950)
// B=8192, D=128, S=64. Output: scalar fp32.
//
// loss = sum_i -log(1e-12 + num_i/denom_i) / (B*(2B-1))
//        + sum_i -log(1e-12 + 1 - picked_i)
//
// v9 structure:
//  - Harness floor: ~42us 256MiB workspace re-poison fill inside the timed
//    region. Our kernels sit on top.
//  - main: back to 16x16x32 MFMA (v8 lesson: 32x32 single serial 8-chain is
//    latency-bound). Two fixes vs v7:
//    (a) 32 rows/wave (afrag 32 regs) -> combined VGPR+AGPR ~<128 -> 16
//        waves/CU (r7 counter showed v6-v8 ran at ~27-31% occupancy = ~8/CU,
//        register-capped).
//    (b) intra-wave MFMA/exp software pipeline (named cA/cB): exp2+add of
//        tile g-1 overlaps the MFMA chain of tile g -> VALU and matrix pipes
//        concurrent WITHIN a wave instead of relying on inter-wave drift.
//    Whole 64KB col-chunk prestaged (global_load_lds), ONE __syncthreads,
//    barrier-free free-run phases (v7 winner). T2t float4 stores.
//  - prep: v7 version (16-row fragment tiles, LDS-staged coalesced stores).
//  - final_adv: 2048 blocks, partial plain store; 1-block reduce sums.
// ---------------------------------------------------------------------------

#define NROWS 8192
#define DFEAT 128

typedef __bf16 bf16_t;
typedef __bf16 bf16x8 __attribute__((ext_vector_type(8)));
typedef __bf16 bf16x2 __attribute__((ext_vector_type(2)));
typedef float  f32x4  __attribute__((ext_vector_type(4)));

__device__ __forceinline__ float fexp2(float x) {
#if __has_builtin(__builtin_amdgcn_exp2f)
  return __builtin_amdgcn_exp2f(x);
#else
  return exp2f(x);
#endif
}

// async global->LDS, 16B per lane. gsrc is per-lane (includes +lane*16);
// lds dst is wave-uniform base (HW adds lane*16).
__device__ __forceinline__ void stage16(const void* gsrc, void* ldst) {
  __builtin_amdgcn_global_load_lds(
      (const __attribute__((address_space(1))) unsigned int*)gsrc,
      (__attribute__((address_space(3))) unsigned int*)ldst, 16, 0, 0);
}

// ---------------------------------------------------------------------------
// prep: block = 16 rows = one fragment-tile group. Wave w normalizes row w
// into padded LDS (stride 136 bf16 = 272B). Then threads 0..767 write the
// A / K2 / K1 fragment-tile groups as contiguous coalesced 16B stores:
//   out[tile*2048 + u*8 + j] = L[u&15][(u>>6)*32 + ((u>>4)&3)*8 + j]
// matching the main kernel's fragment layout.
__global__ __launch_bounds__(1024)
void sa_prep_kernel(const float* __restrict__ z1,
                    const float* __restrict__ z2,
                    bf16_t* __restrict__ Abuf,
                    bf16_t* __restrict__ Kc,
                    float* __restrict__ numv,
                    float* __restrict__ d11v) {
  __shared__ __align__(16) bf16_t LA[16][136];
  __shared__ __align__(16) bf16_t LK2[16][136];
  __shared__ __align__(16) bf16_t LK1[16][136];

  int wave = threadIdx.x >> 6;   // 0..15 : row within tile
  int lane = threadIdx.x & 63;
  int tile = blockIdx.x;         // 0..511
  int row  = tile * 16 + wave;

  float2 a = ((const float2*)(z1 + (size_t)row * DFEAT))[lane];
  float2 b = ((const float2*)(z2 + (size_t)row * DFEAT))[lane];

  float s1  = a.x * a.x + a.y * a.y;
  float s2  = b.x * b.x + b.y * b.y;
  float s12 = a.x * b.x + a.y * b.y;
#pragma unroll
  for (int m = 32; m; m >>= 1) {
    s1  += __shfl_xor(s1, m, 64);
    s2  += __shfl_xor(s2, m, 64);
    s12 += __shfl_xor(s12, m, 64);
  }
  float r1 = 1.0f / fmaxf(sqrtf(s1), 1e-8f);  // COS_EPS
  float r2 = 1.0f / fmaxf(sqrtf(s2), 1e-8f);

  const float SCL = 14.426950408889634f;  // 10 * log2(e), folds /tau + exp2

  bf16x2 av;  av[0] = (bf16_t)(a.x * r1 * SCL); av[1] = (bf16_t)(a.y * r1 * SCL);
  bf16x2 k2v; k2v[0] = (bf16_t)(b.x * r2);      k2v[1] = (bf16_t)(b.y * r2);
  bf16x2 k1v; k1v[0] = (bf16_t)(a.x * r1);      k1v[1] = (bf16_t)(a.y * r1);

  *(bf16x2*)&LA[wave][2 * lane]  = av;
  *(bf16x2*)&LK2[wave][2 * lane] = k2v;
  *(bf16x2*)&LK1[wave][2 * lane] = k1v;

  if (lane == 0) {
    numv[row] = expf(10.0f * s12 * r1 * r2);
    d11v[row] = expf(10.0f * s1 * r1 * r1);
  }
  __syncthreads();

  int t = threadIdx.x;
  if (t < 768) {
    int sel = t >> 8;          // 0=A, 1=K2, 2=K1
    int u   = t & 255;
    int kf  = u >> 6;
    int qk  = (u >> 4) & 3;
    int r16 = u & 15;
    const bf16_t* Ls = (sel == 0) ? &LA[0][0]
                     : (sel == 1) ? &LK2[0][0] : &LK1[0][0];
    bf16x8 v = *(const bf16x8*)(Ls + r16 * 136 + kf * 32 + qk * 8);
    bf16_t* dst = (sel == 0) ? (Abuf + (size_t)tile * 2048)
                : (sel == 1) ? (Kc + (size_t)tile * 2048)
                             : (Kc + (size_t)(512 + tile) * 2048);
    *(bf16x8*)(dst + u * 8) = v;
  }
}

// ---------------------------------------------------------------------------
// main: fused "row-sum of exp(sim)" over the virtual 8192x16384 matrix.
// Block = 256 rows x 256 cols; 8 waves; wave w owns rows [bx*256+w*32, +32).
// Prologue: whole 64KB chunk of Kc staged into LDS (8 x global_load_lds per
// wave), ONE __syncthreads, then barrier-free free-run.
// 16 half-phase tiles (16 cols each), software-pipelined: MFMA chain of
// tile g (8 x mfma_16x16x32 into cB) runs while exp2+add of tile g-1 (cA)
// executes -> matrix and VALU pipes concurrent within the wave.
// MFMA C/D layout: col=lane&15, row=(lane>>4)*4+reg.
// Partial row-sums -> T2t[by][row], float4-coalesced writer lanes.
__global__ __launch_bounds__(512, 4)
void sa_main_kernel(const bf16_t* __restrict__ Abuf,
                    const bf16_t* __restrict__ Kc,
                    float* __restrict__ T2t) {
  __shared__ __align__(16) bf16_t bsm[32768];  // 64KB: 8 col-tiles x 8KB

  int wave = threadIdx.x >> 6;   // 0..7
  int lane = threadIdx.x & 63;
  int quad = lane >> 4;

  // bijective XCD swizzle: 2048 blocks, 8 XCDs, 256 each. Each XCD sweeps
  // 8 col-chunks (512KB of Kc) + all of A (2MB) -> L2-resident.
  int id     = blockIdx.x;
  int xcd    = id & 7;
  int within = id >> 3;                 // 0..255
  int by     = xcd * 8 + (within >> 5); // 0..63 col-chunk: 256 cols
  int bx     = within & 31;             // 0..31 row-block: 256 rows
  int rowBase = bx * 256 + wave * 32;

  // A fragments for this wave's 2 row-strips (fragment-tiled: consecutive
  // 1KB fragments, fully coalesced 16B/lane).
  const bf16x8* ap = (const bf16x8*)Abuf + (size_t)(rowBase >> 4) * 256 + lane;
  bf16x8 afrag[2][4];
#pragma unroll
  for (int s = 0; s < 2; ++s)
#pragma unroll
    for (int kfi = 0; kfi < 4; ++kfi)
      afrag[s][kfi] = ap[(s * 4 + kfi) * 64];

  // Stage the whole 64KB chunk: wave w covers bytes [w*8KB, (w+1)*8KB).
  const char* src = (const char*)Kc + (size_t)by * 65536 +
                    (size_t)wave * 8192 + (size_t)lane * 16;
  char* dst = (char*)&bsm[0] + wave * 8192;  // wave-uniform LDS dst
#pragma unroll
  for (int i = 0; i < 8; ++i) stage16(src + i * 1024, dst + i * 1024);

  __syncthreads();  // only barrier; LDS read-only afterwards

  f32x4 sums[2];
#pragma unroll
  for (int s = 0; s < 2; ++s) sums[s] = (f32x4){0.f, 0.f, 0.f, 0.f};

  // half-phase tile g (0..15): phase p = (wave + g/2) & 7, half = g & 1.
  auto ldb = [&](int g, bf16x8 (&bfr)[4]) {
    int p = (wave + (g >> 1)) & 7;
    const bf16x8* bs =
        (const bf16x8*)(&bsm[0] + p * 4096 + (g & 1) * 2048);
#pragma unroll
    for (int kfi = 0; kfi < 4; ++kfi) bfr[kfi] = bs[kfi * 64 + lane];
  };
  auto mm = [&](const bf16x8 (&bfr)[4], f32x4 (&c)[2]) {
#pragma unroll
    for (int s = 0; s < 2; ++s) {
      f32x4 acc = {0.f, 0.f, 0.f, 0.f};
#pragma unroll
      for (int kfi = 0; kfi < 4; ++kfi)
        acc = __builtin_amdgcn_mfma_f32_16x16x32_bf16(afrag[s][kfi], bfr[kfi],
                                                      acc, 0, 0, 0);
      c[s] = acc;
    }
  };
  auto ex = [&](const f32x4 (&c)[2]) {
#pragma unroll
    for (int s = 0; s < 2; ++s)
#pragma unroll
      for (int r = 0; r < 4; ++r) sums[s][r] += fexp2(c[s][r]);
  };

  bf16x8 bA[4], bB[4];
  f32x4 cA[2], cB[2];

  // prologue: tile 0 -> cA
  ldb(0, bA);
  mm(bA, cA);
  // steady state: MFMA(g) overlaps exp(g-1); named buffers, static indexing.
#pragma unroll 1
  for (int g = 1; g <= 13; g += 2) {
    ldb(g, bB);
    mm(bB, cB);
    ex(cA);                 // overlaps the cB MFMA chain above
    ldb(g + 1, bA);
    mm(bA, cA);
    ex(cB);                 // overlaps the cA MFMA chain above
  }
  ldb(15, bB);
  mm(bB, cB);
  ex(cA);
  ex(cB);

  // Reduce across the 16 lanes of each quad-group (cols); writer lane packs
  // its 4 row-sums into ONE float4 store (quads 0..3 -> contiguous 64B).
  int l15 = lane & 15;
#pragma unroll
  for (int s = 0; s < 2; ++s) {
    f32x4 st;
#pragma unroll
    for (int r = 0; r < 4; ++r) {
      float v = sums[s][r];
      v += __shfl_xor(v, 1, 64);
      v += __shfl_xor(v, 2, 64);
      v += __shfl_xor(v, 4, 64);
      v += __shfl_xor(v, 8, 64);
      st[r] = v;
    }
    if (l15 == 0)
      *(f32x4*)(T2t + (size_t)by * 8192 + rowBase + s * 16 + quad * 4) = st;
  }
}

// ---------------------------------------------------------------------------
// final+adv fused: 2048 blocks x 256 threads, one row per wave, fully
// parallel. Lane l contributes T2t[l][row] (L2-resident 2MB); summed in the
// same 64-lane butterfly as the adversarial argmax. Partial -> plain store.
__global__ __launch_bounds__(256)
void sa_final_adv_kernel(const float* __restrict__ T2t,
                         const float* __restrict__ numv,
                         const float* __restrict__ d11v,
                         const float* __restrict__ c,
                         const float* __restrict__ lab,
                         float* __restrict__ partial) {
  int wave = threadIdx.x >> 6;
  int lane = threadIdx.x & 63;
  int row  = blockIdx.x * 4 + wave;

  float cv = c[row * 64 + lane];
  float lv = lab[row * 64 + lane];
  float tv = T2t[(size_t)lane * 8192 + row];  // 64 chunk-partials per row

  float ss = cv * cv;
  float bestv = lv;
  int   besti = lane;
#pragma unroll
  for (int m = 32; m; m >>= 1) {
    ss += __shfl_xor(ss, m, 64);
    tv += __shfl_xor(tv, m, 64);
    float ov = __shfl_xor(bestv, m, 64);
    int   oi = __shfl_xor(besti, m, 64);
    if (ov > bestv || (ov == bestv && oi < besti)) { bestv = ov; besti = oi; }
  }
  float picked = __shfl(cv, besti, 64) / fmaxf(sqrtf(ss), 1e-12f);

  float term = 0.0f;
  if (lane == 0) {
    float denom = tv - d11v[row];  // tv = full row sum of both exp blocks
    term = -logf(1e-12f + numv[row] / denom) * (1.0f / 134209536.0f)
           - logf(1e-12f + 1.0f - picked);  // LAM = 1
  }

  __shared__ float wacc[4];
  if (lane == 0) wacc[wave] = term;
  __syncthreads();
  if (threadIdx.x == 0)
    partial[blockIdx.x] = wacc[0] + wacc[1] + wacc[2] + wacc[3];
}

// ---------------------------------------------------------------------------
// reduce: single block sums the 2048 block partials -> out (plain store).
__global__ __launch_bounds__(256)
void sa_reduce_kernel(const float* __restrict__ partial,
                      float* __restrict__ out) {
  float v = 0.0f;
#pragma unroll
  for (int i = 0; i < 8; ++i) v += partial[threadIdx.x + 256 * i];
#pragma unroll
  for (int m = 32; m; m >>= 1) v += __shfl_xor(v, m, 64);
  __shared__ float wacc[4];
  if ((threadIdx.x & 63) == 0) wacc[threadIdx.x >> 6] = v;
  __syncthreads();
  if (threadIdx.x == 0) out[0] = wacc[0] + wacc[1] + wacc[2] + wacc[3];
}

// ---------------------------------------------------------------------------
extern "C" void kernel_launch(void* const* d_in, const int* in_sizes, int n_in,
                              void* d_out, int out_size, void* d_ws,
                              size_t ws_size, hipStream_t stream) {
  const float* z1  = (const float*)d_in[0];  // [8192,128]
  const float* z2  = (const float*)d_in[1];  // [8192,128]
  const float* co  = (const float*)d_in[2];  // [8192,64]
  const float* lab = (const float*)d_in[3];  // [8192,64]
  float* out = (float*)d_out;

  char* ws = (char*)d_ws;
  bf16_t* Abuf  = (bf16_t*)ws;                           // 8192*128*2 = 2 MB
  bf16_t* Kc    = (bf16_t*)(ws + 2u * 1024 * 1024);      // 16384*128*2 = 4 MB
  float*  T2t   = (float*)(ws + 6u * 1024 * 1024);       // 64*8192*4 = 2 MB
  float*  numv  = (float*)(ws + 8u * 1024 * 1024);       // 32 KB
  float*  d11v  = numv + NROWS;                          // 32 KB
  float*  part  = d11v + NROWS;                          // 8 KB

  sa_prep_kernel<<<NROWS / 16, 1024, 0, stream>>>(z1, z2, Abuf, Kc, numv,
                                                  d11v);
  sa_main_kernel<<<2048, 512, 0, stream>>>(Abuf, Kc, T2t);
  sa_final_adv_kernel<<<NROWS / 4, 256, 0, stream>>>(T2t, numv, d11v, co, lab,
                                                     part);
  sa_reduce_kernel<<<1, 256, 0, stream>>>(part, out);
}

// Round 9
// 108.109 us; speedup vs baseline: 1.1065x; 1.0289x over previous
//
#include <hip/hip_runtime.h>
#include <hip/hip_bf16.h>
#include <math.h>

// ---------------------------------------------------------------------------
// SAContrastiveAdversarialLoss on MI355X (gfx950)
// B=8192, D=128, S=64. Output: scalar fp32.
//
// loss = sum_i -log(1e-12 + num_i/denom_i) / (B*(2B-1))
//        + sum_i -log(1e-12 + 1 - picked_i)
//
// v10 structure:
//  - Harness floor: ~43us 256MiB workspace re-poison fill inside the timed
//    region. Our kernels sit on top.
//  - main: EXACT v7 (measured best: 16x16x32 MFMA, 64 rows/wave, 64KB
//    full-chunk prestage, one __syncthreads, barrier-free free-run phases).
//    v8 (32x32 serial chain), v9 (mm/ex pipeline @32rows) both regressed;
//    register arithmetic closes the pipeline branch: 64-row pipeline needs
//    ~145 unified regs > 128 band -> 2 waves/SIMD collapse.
//  - prep: 512 blocks x 256 thr (was 1024 thr): wave normalizes 4 rows
//    (unrolled), LDS-staged, coalesced fragment-tile stores. Better ramp.
//  - final_adv: 512 blocks x 256 thr, 4 rows/wave loop; partial[512] plain
//    stores; reduce sums 512 partials -> out.
// ---------------------------------------------------------------------------

#define NROWS 8192
#define DFEAT 128

typedef __bf16 bf16_t;
typedef __bf16 bf16x8 __attribute__((ext_vector_type(8)));
typedef __bf16 bf16x2 __attribute__((ext_vector_type(2)));
typedef float  f32x4  __attribute__((ext_vector_type(4)));

__device__ __forceinline__ float fexp2(float x) {
#if __has_builtin(__builtin_amdgcn_exp2f)
  return __builtin_amdgcn_exp2f(x);
#else
  return exp2f(x);
#endif
}

// async global->LDS, 16B per lane. gsrc is per-lane (includes +lane*16);
// lds dst is wave-uniform base (HW adds lane*16).
__device__ __forceinline__ void stage16(const void* gsrc, void* ldst) {
  __builtin_amdgcn_global_load_lds(
      (const __attribute__((address_space(1))) unsigned int*)gsrc,
      (__attribute__((address_space(3))) unsigned int*)ldst, 16, 0, 0);
}

// ---------------------------------------------------------------------------
// prep: block = 16 rows = one fragment-tile group, 256 threads (4 waves).
// Wave w normalizes rows 4w..4w+3 into padded LDS (stride 136 bf16 = 272B).
// Then 3 x 256 coalesced bf16x8 stores emit the A / K2 / K1 fragment tiles:
//   out[tile*2048 + u*8 + j] = L[u&15][(u>>6)*32 + ((u>>4)&3)*8 + j]
// matching the main kernel's fragment layout.
__global__ __launch_bounds__(256)
void sa_prep_kernel(const float* __restrict__ z1,
                    const float* __restrict__ z2,
                    bf16_t* __restrict__ Abuf,
                    bf16_t* __restrict__ Kc,
                    float* __restrict__ numv,
                    float* __restrict__ d11v) {
  __shared__ __align__(16) bf16_t L[3][16][136];

  int wave = threadIdx.x >> 6;   // 0..3
  int lane = threadIdx.x & 63;
  int tile = blockIdx.x;         // 0..511

  const float SCL = 14.426950408889634f;  // 10 * log2(e), folds /tau + exp2

#pragma unroll
  for (int r = 0; r < 4; ++r) {
    int rl  = wave * 4 + r;      // 0..15 row within tile
    int row = tile * 16 + rl;

    float2 a = ((const float2*)(z1 + (size_t)row * DFEAT))[lane];
    float2 b = ((const float2*)(z2 + (size_t)row * DFEAT))[lane];

    float s1  = a.x * a.x + a.y * a.y;
    float s2  = b.x * b.x + b.y * b.y;
    float s12 = a.x * b.x + a.y * b.y;
#pragma unroll
    for (int m = 32; m; m >>= 1) {
      s1  += __shfl_xor(s1, m, 64);
      s2  += __shfl_xor(s2, m, 64);
      s12 += __shfl_xor(s12, m, 64);
    }
    float r1 = 1.0f / fmaxf(sqrtf(s1), 1e-8f);  // COS_EPS
    float r2 = 1.0f / fmaxf(sqrtf(s2), 1e-8f);

    bf16x2 av;  av[0] = (bf16_t)(a.x * r1 * SCL); av[1] = (bf16_t)(a.y * r1 * SCL);
    bf16x2 k2v; k2v[0] = (bf16_t)(b.x * r2);      k2v[1] = (bf16_t)(b.y * r2);
    bf16x2 k1v; k1v[0] = (bf16_t)(a.x * r1);      k1v[1] = (bf16_t)(a.y * r1);

    *(bf16x2*)&L[0][rl][2 * lane] = av;
    *(bf16x2*)&L[1][rl][2 * lane] = k2v;
    *(bf16x2*)&L[2][rl][2 * lane] = k1v;

    if (lane == 0) {
      numv[row] = expf(10.0f * s12 * r1 * r2);
      d11v[row] = expf(10.0f * s1 * r1 * r1);
    }
  }
  __syncthreads();

  // Phase 2: 3 x 256 coalesced 16B stores (A, K2, K1 tiles).
#pragma unroll
  for (int sel = 0; sel < 3; ++sel) {
    int u   = threadIdx.x;       // 0..255
    int kf  = u >> 6;
    int qk  = (u >> 4) & 3;
    int r16 = u & 15;
    bf16x8 v = *(const bf16x8*)&L[sel][r16][kf * 32 + qk * 8];
    bf16_t* dst = (sel == 0) ? (Abuf + (size_t)tile * 2048)
                : (sel == 1) ? (Kc + (size_t)tile * 2048)
                             : (Kc + (size_t)(512 + tile) * 2048);
    *(bf16x8*)(dst + u * 8) = v;
  }
}

// ---------------------------------------------------------------------------
// main (EXACT v7): fused "row-sum of exp(sim)" over the 8192x16384 matrix.
// Block = 512 rows x 256 cols; 8 waves; wave w owns rows [bx*512+w*64, +64).
// Prologue: whole 64KB chunk of Kc staged into LDS (8 x global_load_lds per
// wave), ONE __syncthreads, then barrier-free rotated free-run phases.
// MFMA C/D layout: col=lane&15, row=(lane>>4)*4+reg.
// Partial row-sums -> T2t[by][row], float4-coalesced writer lanes.
__global__ __launch_bounds__(512, 4)
void sa_main_kernel(const bf16_t* __restrict__ Abuf,
                    const bf16_t* __restrict__ Kc,
                    float* __restrict__ T2t) {
  __shared__ __align__(16) bf16_t bsm[32768];  // 64KB: 8 col-tiles x 8KB

  int wave = threadIdx.x >> 6;   // 0..7
  int lane = threadIdx.x & 63;
  int quad = lane >> 4;

  // bijective XCD swizzle: 1024 blocks, 8 XCDs, 128 each. Each XCD sweeps
  // 8 col-chunks (512KB of Kc) + all of A (2MB) -> L2-resident.
  int id     = blockIdx.x;
  int xcd    = id & 7;
  int within = id >> 3;                 // 0..127
  int by     = xcd * 8 + (within >> 4); // 0..63 col-chunk: 256 cols
  int bx     = within & 15;             // 0..15 row-block: 512 rows
  int rowBase = bx * 512 + wave * 64;

  // A fragments for this wave's 4 row-strips (fragment-tiled: consecutive
  // 1KB fragments, fully coalesced 16B/lane).
  const bf16x8* ap = (const bf16x8*)Abuf + (size_t)(rowBase >> 4) * 256 + lane;
  bf16x8 afrag[4][4];
#pragma unroll
  for (int s = 0; s < 4; ++s)
#pragma unroll
    for (int kfi = 0; kfi < 4; ++kfi)
      afrag[s][kfi] = ap[(s * 4 + kfi) * 64];

  // Stage the whole 64KB chunk: wave w covers bytes [w*8KB, (w+1)*8KB).
  const char* src = (const char*)Kc + (size_t)by * 65536 +
                    (size_t)wave * 8192 + (size_t)lane * 16;
  char* dst = (char*)&bsm[0] + wave * 8192;  // wave-uniform LDS dst
#pragma unroll
  for (int i = 0; i < 8; ++i) stage16(src + i * 1024, dst + i * 1024);

  __syncthreads();  // only barrier in the kernel; LDS read-only afterwards

  f32x4 sums[4];
#pragma unroll
  for (int s = 0; s < 4; ++s) sums[s] = (f32x4){0.f, 0.f, 0.f, 0.f};

  // 8 phases x 32 cols, rotated start per wave; no sync, waves free-run.
#pragma unroll 1
  for (int i = 0; i < 8; ++i) {
    int p = (wave + i) & 7;
    const bf16_t* base = &bsm[0] + p * 4096;
#pragma unroll
    for (int tt = 0; tt < 2; ++tt) {
      const bf16x8* bs = (const bf16x8*)(base + tt * 2048);
      bf16x8 bfr[4];
#pragma unroll
      for (int kfi = 0; kfi < 4; ++kfi) bfr[kfi] = bs[kfi * 64 + lane];
#pragma unroll
      for (int s = 0; s < 4; ++s) {
        f32x4 c = {0.f, 0.f, 0.f, 0.f};
        __builtin_amdgcn_s_setprio(1);
#pragma unroll
        for (int kfi = 0; kfi < 4; ++kfi)
          c = __builtin_amdgcn_mfma_f32_16x16x32_bf16(afrag[s][kfi], bfr[kfi],
                                                      c, 0, 0, 0);
        __builtin_amdgcn_s_setprio(0);
#pragma unroll
        for (int r = 0; r < 4; ++r) sums[s][r] += fexp2(c[r]);
      }
    }
  }

  // Reduce across the 16 lanes of each quad-group (cols); writer lane packs
  // its 4 row-sums into ONE float4 store (quads 0..3 -> contiguous 64B).
  int l15 = lane & 15;
#pragma unroll
  for (int s = 0; s < 4; ++s) {
    f32x4 st;
#pragma unroll
    for (int r = 0; r < 4; ++r) {
      float v = sums[s][r];
      v += __shfl_xor(v, 1, 64);
      v += __shfl_xor(v, 2, 64);
      v += __shfl_xor(v, 4, 64);
      v += __shfl_xor(v, 8, 64);
      st[r] = v;
    }
    if (l15 == 0)
      *(f32x4*)(T2t + (size_t)by * 8192 + rowBase + s * 16 + quad * 4) = st;
  }
}

// ---------------------------------------------------------------------------
// final+adv fused: 512 blocks x 256 threads; wave handles 4 rows (loop).
// Lane l contributes T2t[l][row] (L2-resident 2MB); summed in the same
// 64-lane butterfly as the adversarial argmax. Partial -> plain store.
__global__ __launch_bounds__(256)
void sa_final_adv_kernel(const float* __restrict__ T2t,
                         const float* __restrict__ numv,
                         const float* __restrict__ d11v,
                         const float* __restrict__ c,
                         const float* __restrict__ lab,
                         float* __restrict__ partial) {
  int wave = threadIdx.x >> 6;
  int lane = threadIdx.x & 63;

  float acc = 0.0f;
#pragma unroll
  for (int i = 0; i < 4; ++i) {
    int row = blockIdx.x * 16 + wave * 4 + i;

    float cv = c[row * 64 + lane];
    float lv = lab[row * 64 + lane];
    float tv = T2t[(size_t)lane * 8192 + row];  // 64 chunk-partials per row

    float ss = cv * cv;
    float bestv = lv;
    int   besti = lane;
#pragma unroll
    for (int m = 32; m; m >>= 1) {
      ss += __shfl_xor(ss, m, 64);
      tv += __shfl_xor(tv, m, 64);
      float ov = __shfl_xor(bestv, m, 64);
      int   oi = __shfl_xor(besti, m, 64);
      if (ov > bestv || (ov == bestv && oi < besti)) { bestv = ov; besti = oi; }
    }
    float picked = __shfl(cv, besti, 64) / fmaxf(sqrtf(ss), 1e-12f);

    if (lane == 0) {
      float denom = tv - d11v[row];  // tv = full row sum of both exp blocks
      acc += -logf(1e-12f + numv[row] / denom) * (1.0f / 134209536.0f)
             - logf(1e-12f + 1.0f - picked);  // LAM = 1
    }
  }

  __shared__ float wacc[4];
  if (lane == 0) wacc[wave] = acc;
  __syncthreads();
  if (threadIdx.x == 0)
    partial[blockIdx.x] = wacc[0] + wacc[1] + wacc[2] + wacc[3];
}

// ---------------------------------------------------------------------------
// reduce: single block sums the 512 block partials -> out (plain store).
__global__ __launch_bounds__(256)
void sa_reduce_kernel(const float* __restrict__ partial,
                      float* __restrict__ out) {
  float v = partial[threadIdx.x] + partial[threadIdx.x + 256];
#pragma unroll
  for (int m = 32; m; m >>= 1) v += __shfl_xor(v, m, 64);
  __shared__ float wacc[4];
  if ((threadIdx.x & 63) == 0) wacc[threadIdx.x >> 6] = v;
  __syncthreads();
  if (threadIdx.x == 0) out[0] = wacc[0] + wacc[1] + wacc[2] + wacc[3];
}

// ---------------------------------------------------------------------------
extern "C" void kernel_launch(void* const* d_in, const int* in_sizes, int n_in,
                              void* d_out, int out_size, void* d_ws,
                              size_t ws_size, hipStream_t stream) {
  const float* z1  = (const float*)d_in[0];  // [8192,128]
  const float* z2  = (const float*)d_in[1];  // [8192,128]
  const float* co  = (const float*)d_in[2];  // [8192,64]
  const float* lab = (const float*)d_in[3];  // [8192,64]
  float* out = (float*)d_out;

  char* ws = (char*)d_ws;
  bf16_t* Abuf  = (bf16_t*)ws;                           // 8192*128*2 = 2 MB
  bf16_t* Kc    = (bf16_t*)(ws + 2u * 1024 * 1024);      // 16384*128*2 = 4 MB
  float*  T2t   = (float*)(ws + 6u * 1024 * 1024);       // 64*8192*4 = 2 MB
  float*  numv  = (float*)(ws + 8u * 1024 * 1024);       // 32 KB
  float*  d11v  = numv + NROWS;                          // 32 KB
  float*  part  = d11v + NROWS;                          // 2 KB

  sa_prep_kernel<<<NROWS / 16, 256, 0, stream>>>(z1, z2, Abuf, Kc, numv,
                                                 d11v);
  sa_main_kernel<<<1024, 512, 0, stream>>>(Abuf, Kc, T2t);
  sa_final_adv_kernel<<<NROWS / 16, 256, 0, stream>>>(T2t, numv, d11v, co,
                                                      lab, part);
  sa_reduce_kernel<<<1, 256, 0, stream>>>(part, out);
}